// Round 16
// baseline (220.828 us; speedup 1.0000x reference)
//
#include <hip/hip_runtime.h>
#include <stdint.h>

// Problem constants
#define L_    8192
#define N_    8
#define L2_   2048
#define K_    16

typedef unsigned int uint;
typedef unsigned short ushort;
typedef unsigned long long u64;
typedef __attribute__((ext_vector_type(8))) short bh8;   // 8 bf16 (4 VGPRs)
typedef __attribute__((ext_vector_type(4))) float f32x4; // MFMA C/D

// round-to-nearest-even f32 -> bf16 (monotone)
__device__ __forceinline__ ushort f2b(float f){
  uint u = __float_as_uint(f);
  return (ushort)((u + 0x7FFFu + ((u >> 16) & 1u)) >> 16);
}
// monotone float->uint mapping (handles tiny negative self-distances)
__device__ __forceinline__ uint ford(float f){
  uint u = __float_as_uint(f);
  return u ^ ((uint)((int)u >> 31) | 0x80000000u);
}
// inverse of ford
__device__ __forceinline__ float unford(uint u){
  uint v = (u & 0x80000000u) ? (u ^ 0x80000000u) : ~u;
  return __uint_as_float(v);
}

__device__ __forceinline__ void ld8(float* t, const float* p){
  float4 a = *(const float4*)p; float4 b = *(const float4*)(p + 4);
  t[0]=a.x; t[1]=a.y; t[2]=a.z; t[3]=a.w; t[4]=b.x; t[5]=b.y; t[6]=b.z; t[7]=b.w;
}
__device__ __forceinline__ bh8 pack8(const float* v){
  bh8 r;
  #pragma unroll
  for (int j = 0; j < 8; ++j) r[j] = (short)f2b(v[j]);
  return r;
}

// ---------------- K1: norm-sort prep + weight pack + keep_coords ----------------
// 1024-thr blocks. blk 0..7: per-n bucket sort of candidates by |c|^2 ->
//   cFs[n][8192] (float4 x,y,z,cc, ascending-ish cc), ord[n][8192] (orig l, u16),
//   sg[n][16] = (sqrt(min cc), sqrt(max cc)) per 512-candidate group.
// blk 8..31: pack w1+w2 f32->bf16. blk 32..79: keep_coords gather.
__global__ __launch_bounds__(1024) void prep_sort_k(const float* __restrict__ coords,
                                                    const int* __restrict__ keep,
                                                    const float* __restrict__ w1,
                                                    const float* __restrict__ w2,
                                                    float4* __restrict__ cFs,
                                                    ushort* __restrict__ ord,
                                                    float2* __restrict__ sg,
                                                    float* __restrict__ out0,
                                                    ushort* __restrict__ pw1,
                                                    ushort* __restrict__ pw2){
  int blk = blockIdx.x;
  int tid = threadIdx.x;
  if (blk >= 8){
    if (blk < 32){
      int e = (blk - 8) * 1024 + tid;          // e < 24576
      if (e < 8192) pw1[e] = f2b(w1[e]);
      else          pw2[e - 8192] = f2b(w2[e - 8192]);
    } else {
      int t = (blk - 32) * 1024 + tid;         // t < 49152 = L2*N*3
      int i = t / 24; int rem = t - i * 24;
      out0[t] = coords[(size_t)keep[i] * 24 + rem];
    }
    return;
  }

  __shared__ uint hist[4096];                  // 16 KB
  __shared__ uint wtot[16];
  __shared__ uint gmn[16], gmx[16];
  int n = blk;
  int lane = tid & 63, wv = tid >> 6;

  // load 8 candidates (l = tid + k*1024), compute cc with np association
  float xs[8], ys[8], zs[8], cs[8];
  #pragma unroll
  for (int k = 0; k < 8; ++k){
    int l = tid + (k << 10);
    const float* cr = coords + ((size_t)l * 8 + n) * 3;
    xs[k] = cr[0]; ys[k] = cr[1]; zs[k] = cr[2];
    {
      #pragma clang fp contract(off)
      cs[k] = xs[k]*xs[k] + ys[k]*ys[k] + zs[k]*zs[k];
    }
  }
  #pragma unroll
  for (int j = 0; j < 4; ++j) hist[tid * 4 + j] = 0;
  __syncthreads();
  uint bk[8];
  #pragma unroll
  for (int k = 0; k < 8; ++k){
    bk[k] = min(4095u, (uint)(cs[k] * 91.0f));
    atomicAdd(&hist[bk[k]], 1u);
  }
  __syncthreads();
  // block exclusive prefix over 4096 buckets (thread owns 4)
  uint c0 = hist[tid*4], c1 = hist[tid*4+1], c2 = hist[tid*4+2], c3 = hist[tid*4+3];
  uint s = c0 + c1 + c2 + c3;
  uint incl = s;
  #pragma unroll
  for (int o = 1; o < 64; o <<= 1){
    uint v = (uint)__shfl_up((int)incl, o, 64);
    if (lane >= o) incl += v;
  }
  if (lane == 63) wtot[wv] = incl;
  __syncthreads();
  uint wbase = 0;
  for (int w = 0; w < wv; ++w) wbase += wtot[w];
  uint base0 = wbase + incl - s;
  __syncthreads();                             // all reads of hist counts done
  hist[tid*4+0] = base0;
  hist[tid*4+1] = base0 + c0;
  hist[tid*4+2] = base0 + c0 + c1;
  hist[tid*4+3] = base0 + c0 + c1 + c2;
  __syncthreads();
  // scatter (bucket-internal order arbitrary; harmless — selection keys are exact)
  #pragma unroll
  for (int k = 0; k < 8; ++k){
    uint pos = atomicAdd(&hist[bk[k]], 1u);
    cFs[((size_t)n << 13) + pos] = make_float4(xs[k], ys[k], zs[k], cs[k]);
    ord[(n << 13) + pos] = (ushort)(tid + (k << 10));
  }
  __syncthreads();                             // drains vmcnt -> global writes visible in-CU
  // per-512-group cc min/max: wave wv covers exactly group wv's elements
  {
    uint mn = 0xFFFFFFFFu, mx = 0u;
    #pragma unroll
    for (int j = 0; j < 8; ++j){
      int e = ((tid >> 3) << 6) + ((tid & 7) << 3) + j;   // e in [wv*512, wv*512+512)
      uint u = __float_as_uint(cFs[((size_t)n << 13) + e].w);  // cc >= 0: bits monotone
      mn = min(mn, u); mx = max(mx, u);
    }
    #pragma unroll
    for (int o = 1; o < 64; o <<= 1){
      mn = min(mn, (uint)__shfl_xor((int)mn, o, 64));
      mx = max(mx, (uint)__shfl_xor((int)mx, o, 64));
    }
    if (lane == 0){ gmn[wv] = mn; gmx[wv] = mx; }
  }
  __syncthreads();
  if (tid < 16)
    sg[n * 16 + tid] = make_float2(sqrtf(__uint_as_float(gmn[tid])),
                                   sqrtf(__uint_as_float(gmx[tid])));
}

// ---------------- K2: MFMA MLP (pre-packed bf16 weights) — R14-identical ----------------
__global__ __launch_bounds__(256) void mlp_k(const float* __restrict__ feat,
                                             const ushort* __restrict__ pw1,
                                             const float* __restrict__ g1,
                                             const float* __restrict__ b1,
                                             const ushort* __restrict__ pw2,
                                             const float* __restrict__ g2,
                                             const float* __restrict__ b2,
                                             uint* __restrict__ fBw){
  __shared__ ushort hlds[64 * 136];
  int tid = threadIdx.x;
  int lane = tid & 63;
  int wv = __builtin_amdgcn_readfirstlane(tid >> 6);
  int quad = lane >> 4, c = lane & 15;
  int rowg = blockIdx.x * 64 + wv * 16;

  bh8 a1[2];
  {
    int rg = rowg + c; int l = rg & 2047, nb = rg >> 11;
    const float* xr = feat + (size_t)((l << 3) + nb) * 64 + quad * 8;
    float t[8];
    ld8(t, xr);      a1[0] = pack8(t);
    ld8(t, xr + 32); a1[1] = pack8(t);
  }

  f32x4 acc1[8];
  #pragma unroll
  for (int t = 0; t < 8; ++t) acc1[t] = (f32x4){0.f, 0.f, 0.f, 0.f};
  #pragma unroll
  for (int s = 0; s < 2; ++s){
    #pragma unroll
    for (int t = 0; t < 8; ++t){
      bh8 wb = *(const bh8*)(pw1 + (size_t)(t * 16 + c) * 64 + s * 32 + quad * 8);
      acc1[t] = __builtin_amdgcn_mfma_f32_16x16x32_bf16(a1[s], wb, acc1[t], 0, 0, 0);
    }
  }

  float mean1[4], rstd1[4];
  #pragma unroll
  for (int r = 0; r < 4; ++r){
    float s = 0.f;
    #pragma unroll
    for (int t = 0; t < 8; ++t) s += acc1[t][r];
    #pragma unroll
    for (int m = 1; m < 16; m <<= 1) s += __shfl_xor(s, m, 16);
    mean1[r] = s * 0.0078125f;
  }
  #pragma unroll
  for (int r = 0; r < 4; ++r){
    float s = 0.f;
    #pragma unroll
    for (int t = 0; t < 8; ++t){ float d = acc1[t][r] - mean1[r]; s += d * d; }
    #pragma unroll
    for (int m = 1; m < 16; m <<= 1) s += __shfl_xor(s, m, 16);
    rstd1[r] = rsqrtf(s * 0.0078125f + 1e-5f);
  }
  ushort* hl = hlds + wv * 16 * 136;
  #pragma unroll
  for (int t = 0; t < 8; ++t){
    float gv = g1[t * 16 + c], bv = b1[t * 16 + c];
    #pragma unroll
    for (int r = 0; r < 4; ++r){
      float v = (acc1[t][r] - mean1[r]) * rstd1[r] * gv + bv;
      hl[(quad * 4 + r) * 136 + t * 16 + c] = f2b(v);
    }
  }

  f32x4 acc2[8];
  #pragma unroll
  for (int t = 0; t < 8; ++t) acc2[t] = (f32x4){0.f, 0.f, 0.f, 0.f};
  #pragma unroll
  for (int s = 0; s < 4; ++s){
    bh8 af = *(const bh8*)(hl + c * 136 + s * 32 + quad * 8);
    #pragma unroll
    for (int t = 0; t < 8; ++t){
      bh8 wb = *(const bh8*)(pw2 + (size_t)(t * 16 + c) * 128 + s * 32 + quad * 8);
      acc2[t] = __builtin_amdgcn_mfma_f32_16x16x32_bf16(af, wb, acc2[t], 0, 0, 0);
    }
  }

  float mean2[4], rstd2[4];
  #pragma unroll
  for (int r = 0; r < 4; ++r){
    float s = 0.f;
    #pragma unroll
    for (int t = 0; t < 8; ++t) s += acc2[t][r];
    #pragma unroll
    for (int m = 1; m < 16; m <<= 1) s += __shfl_xor(s, m, 16);
    mean2[r] = s * 0.0078125f;
  }
  #pragma unroll
  for (int r = 0; r < 4; ++r){
    float s = 0.f;
    #pragma unroll
    for (int t = 0; t < 8; ++t){ float d = acc2[t][r] - mean2[r]; s += d * d; }
    #pragma unroll
    for (int m = 1; m < 16; m <<= 1) s += __shfl_xor(s, m, 16);
    rstd2[r] = rsqrtf(s * 0.0078125f + 1e-5f);
  }
  #pragma unroll
  for (int t = 0; t < 8; ++t){
    float gv = g2[t * 16 + c], bv = b2[t * 16 + c];
    #pragma unroll
    for (int r = 0; r < 4; ++r){
      float v = fmaxf((acc2[t][r] - mean2[r]) * rstd2[r] * gv + bv, 0.f);
      hl[(quad * 4 + r) * 136 + t * 16 + c] = f2b(v);
    }
  }
  {
    int row16 = lane >> 2, chunk = lane & 3;
    const uint* src = (const uint*)hlds + (wv * 16 + row16) * 68 + chunk * 16;
    uint* dst = fBw + (size_t)(rowg + row16) * 64 + chunk * 16;
    #pragma unroll
    for (int j = 0; j < 4; ++j)
      *(uint4*)(dst + j * 4) = *(const uint4*)(src + j * 4);
  }
}

// ---------------- K3: fused KNN + pool, norm-window pruning + shell spiral ----------------
__device__ __forceinline__ u64 shfl64(u64 v, int src){
  int lo = __shfl((int)(uint)v, src, 64);
  int hi = __shfl((int)(uint)(v >> 32), src, 64);
  return ((u64)(uint)hi << 32) | (uint)lo;
}

__device__ __forceinline__ u64 bsort64(u64 key, int lane){
  #pragma unroll
  for (int k = 2; k <= 64; k <<= 1){
    #pragma unroll
    for (int j = k >> 1; j > 0; j >>= 1){
      u64 o = shfl64(key, lane ^ j);
      bool lower = (lane & j) == 0;
      bool down  = (lane & k) == 0;
      bool takeMin = (lower == down);
      bool oLess = o < key;
      key = (oLess == takeMin) ? o : key;
    }
  }
  return key;
}
__device__ __forceinline__ u64 bmerge64(u64 key, int lane){
  #pragma unroll
  for (int j = 32; j > 0; j >>= 1){
    u64 o = shfl64(key, lane ^ j);
    bool lower = (lane & j) == 0;
    bool oLess = o < key;
    key = (oLess == lower) ? o : key;
  }
  return key;
}

__device__ __forceinline__ u64 drain(u64* ldsq, int& qcount, float& hf, int lane){
  u64 a = (lane < qcount) ? ldsq[lane] : ~0ull;
  a = bsort64(a, lane);
  if (qcount > 64){
    u64 b = (64 + lane < qcount) ? ldsq[64 + lane] : ~0ull;
    b = bsort64(b, lane);
    u64 br = shfl64(b, 63 - lane);
    a = a < br ? a : br;
    a = bmerge64(a, lane);
  }
  if (lane < 16) ldsq[lane] = a;
  u64 h = shfl64(a, 15);
  hf = unford((uint)(h >> 32));
  qcount = 16;
  return a;
}

__global__ __launch_bounds__(256) void knn_pool_k(const float4* __restrict__ cFs,
                                                  const ushort* __restrict__ ord,
                                                  const float2* __restrict__ sg,
                                                  const float* __restrict__ coords,
                                                  const int* __restrict__ keep,
                                                  const uint* __restrict__ fB32,
                                                  float* __restrict__ out1){
  __shared__ u64 q8[4][2][128];
  int tid = threadIdx.x, lane = tid & 63;
  int wv = tid >> 6;
  int g0 = blockIdx.x * 8 + wv * 2;
  int n = g0 >> 11;
  int i0 = g0 & 2047, i1 = i0 + 1;
  u64* qlA = q8[wv][0];
  u64* qlB = q8[wv][1];
  // queries from raw coords (same fp association as reference)
  float4 qa, qb;
  {
    const float* c0p = coords + ((size_t)keep[i0] * 8 + n) * 3;
    const float* c1p = coords + ((size_t)keep[i1] * 8 + n) * 3;
    qa.x = c0p[0]; qa.y = c0p[1]; qa.z = c0p[2];
    qb.x = c1p[0]; qb.y = c1p[1]; qb.z = c1p[2];
    {
      #pragma clang fp contract(off)
      qa.w = qa.x*qa.x + qa.y*qa.y + qa.z*qa.z;
    }
    {
      #pragma clang fp contract(off)
      qb.w = qb.x*qb.x + qb.y*qb.y + qb.z*qb.z;
    }
  }
  float skA = sqrtf(qa.w), skB = sqrtf(qb.w);
  const float4* base = cFs + ((size_t)n << 13);
  const ushort* ordn = ord + (n << 13);
  const float2* sgn = sg + n * 16;

  float hfA = 3.4e38f, hfrA = 3.4e38f; int qcA = 0;
  float hfB = 3.4e38f, hfrB = 3.4e38f; int qcB = 0;

  #define PROCQ(q, hfr, hf, qc, ql, cf, jidx) { \
    float dd = __builtin_fmaf(q.x,(cf).x, __builtin_fmaf(q.y,(cf).y, q.z*(cf).z)); \
    float e = __builtin_fmaf(-2.0f, dd, q.w + (cf).w); \
    u64 bal = __ballot(e <= hfr); \
    if (bal){ \
      if (e <= hfr){ \
        float d2; \
        { \
          _Pragma("clang fp contract(off)") \
          float dot = q.x*(cf).x + q.y*(cf).y + q.z*(cf).z; \
          d2 = (q.w + (cf).w) - 2.0f * dot; \
        } \
        uint ol = (uint)ordn[jidx]; \
        int rel = __builtin_amdgcn_mbcnt_lo((uint)bal, 0); \
        rel = __builtin_amdgcn_mbcnt_hi((uint)(bal >> 32), rel); \
        ql[qc + rel] = ((u64)ford(d2) << 32) | ol; \
      } \
      qc += __popcll(bal); \
      if (qc >= 49){ drain(ql, qc, hf, lane); hfr = hf + 1e-3f; } \
    } \
  }
  #define PROC2(cf, jidx) { \
    if (doA) PROCQ(qa, hfrA, hfA, qcA, qlA, cf, jidx) \
    if (doB) PROCQ(qb, hfrB, hfB, qcB, qlB, cf, jidx) \
  }

  // spiral over 16 norm-groups starting at the queries' shell
  int gstart = 0;
  {
    float skM = 0.5f * (skA + skB);
    #pragma unroll
    for (int g = 1; g < 16; ++g) if (sgn[g].x <= skM) gstart = g;
  }
  for (int step = 0; step < 31; ++step){
    int off = (step + 1) >> 1;
    int g = (step & 1) ? gstart - off : gstart + off;
    if (g < 0 || g > 15) continue;
    float2 sv = sgn[g];
    float la = fmaxf(fmaxf(sv.x - skA, skA - sv.y), 0.f);
    float lb = fmaxf(fmaxf(sv.x - skB, skB - sv.y), 0.f);
    bool doA = la * la <= hfA + 0.01f;          // margin >> all fp rounding
    bool doB = lb * lb <= hfB + 0.01f;
    if (!(doA | doB)) continue;
    const float4* p0 = base + (g << 9);
    #pragma unroll
    for (int half = 0; half < 2; ++half){
      const float4* p = p0 + (half << 8) + lane;
      float4 c0 = p[0];
      float4 c1 = p[64];
      float4 c2 = p[128];
      float4 c3 = p[192];
      int j0 = (g << 9) + (half << 8) + lane;
      PROC2(c0, j0);
      PROC2(c1, j0 + 64);
      PROC2(c2, j0 + 128);
      PROC2(c3, j0 + 192);
    }
  }
  u64 aA = drain(qlA, qcA, hfA, lane);
  u64 aB = drain(qlB, qcB, hfB, lane);
  #undef PROC2
  #undef PROCQ

  // fused pool (keys carry ORIGINAL index; fmod(L2) quirk via &2047)
  const uint* frow = fB32 + ((size_t)(n << 11) << 6);
  float a0 = -3.4e38f, a1v = -3.4e38f, b0 = -3.4e38f, b1v = -3.4e38f;
  #pragma unroll
  for (int k = 0; k < 16; ++k){
    int idxA = (int)(shfl64(aA, k) & 2047u);
    int idxB = (int)(shfl64(aB, k) & 2047u);
    uint uA = frow[((size_t)idxA << 6) + lane];
    uint uB = frow[((size_t)idxB << 6) + lane];
    a0  = fmaxf(a0,  __uint_as_float((uA & 0xFFFFu) << 16));
    a1v = fmaxf(a1v, __uint_as_float((uA >> 16) << 16));
    b0  = fmaxf(b0,  __uint_as_float((uB & 0xFFFFu) << 16));
    b1v = fmaxf(b1v, __uint_as_float((uB >> 16) << 16));
  }
  float2* oA = (float2*)(out1 + (size_t)(i0 * 8 + n) * 128);
  float2* oB = (float2*)(out1 + (size_t)(i1 * 8 + n) * 128);
  oA[lane] = make_float2(a0, a1v);
  oB[lane] = make_float2(b0, b1v);
}

extern "C" void kernel_launch(void* const* d_in, const int* in_sizes, int n_in,
                              void* d_out, int out_size, void* d_ws, size_t ws_size,
                              hipStream_t stream){
  const float* coords = (const float*)d_in[0];
  const float* feat   = (const float*)d_in[1];
  const float* w1     = (const float*)d_in[2];
  const float* g1     = (const float*)d_in[3];
  const float* b1     = (const float*)d_in[4];
  const float* w2     = (const float*)d_in[5];
  const float* g2     = (const float*)d_in[6];
  const float* b2     = (const float*)d_in[7];
  const int*   keep   = (const int*)d_in[8];
  float* out0 = (float*)d_out;                    // keep_coords [2048,8,3]
  float* out1 = out0 + 49152;                     // pool_features [2048,8,128]

  char* ws = (char*)d_ws;
  float4* cFs = (float4*)ws;                      // [N][L] sorted f32x4 : 1 MB
  ushort* fB  = (ushort*)(ws + (1 << 20));        // [N][L2][128] bf16 : 4 MB
  ushort* pw1 = (ushort*)(ws + (5 << 20));        // 16 KB packed w1
  ushort* pw2 = pw1 + 8192;                       // 32 KB packed w2
  ushort* ord = (ushort*)(ws + (5 << 20) + (64 << 10));   // [N][L] u16 : 128 KB
  float2* sg  = (float2*)(ws + (5 << 20) + (256 << 10));  // [N][16] f32x2

  hipLaunchKernelGGL(prep_sort_k, dim3(80), dim3(1024), 0, stream,
                     coords, keep, w1, w2, cFs, ord, sg, out0, pw1, pw2);
  hipLaunchKernelGGL(mlp_k, dim3(256), dim3(256), 0, stream,
                     feat, pw1, g1, b1, pw2, g2, b2, (uint*)fB);
  hipLaunchKernelGGL(knn_pool_k, dim3(2048), dim3(256), 0, stream,
                     cFs, ord, sg, coords, keep, (const uint*)fB, out1);
}

// Round 17
// 190.060 us; speedup vs baseline: 1.1619x; 1.1619x over previous
//
#include <hip/hip_runtime.h>
#include <stdint.h>

// Problem constants
#define L_    8192
#define N_    8
#define L2_   2048
#define K_    16

typedef unsigned int uint;
typedef unsigned short ushort;
typedef unsigned long long u64;
typedef __attribute__((ext_vector_type(8))) short bh8;   // 8 bf16 (4 VGPRs)
typedef __attribute__((ext_vector_type(4))) float f32x4; // MFMA C/D

// round-to-nearest-even f32 -> bf16 (monotone)
__device__ __forceinline__ ushort f2b(float f){
  uint u = __float_as_uint(f);
  return (ushort)((u + 0x7FFFu + ((u >> 16) & 1u)) >> 16);
}
// monotone float->uint mapping (handles tiny negative self-distances)
__device__ __forceinline__ uint ford(float f){
  uint u = __float_as_uint(f);
  return u ^ ((uint)((int)u >> 31) | 0x80000000u);
}
// inverse of ford
__device__ __forceinline__ float unford(uint u){
  uint v = (u & 0x80000000u) ? (u ^ 0x80000000u) : ~u;
  return __uint_as_float(v);
}

__device__ __forceinline__ void ld8(float* t, const float* p){
  float4 a = *(const float4*)p; float4 b = *(const float4*)(p + 4);
  t[0]=a.x; t[1]=a.y; t[2]=a.z; t[3]=a.w; t[4]=b.x; t[5]=b.y; t[6]=b.z; t[7]=b.w;
}
__device__ __forceinline__ bh8 pack8(const float* v){
  bh8 r;
  #pragma unroll
  for (int j = 0; j < 8; ++j) r[j] = (short)f2b(v[j]);
  return r;
}

// ---------------- K1: norm-sort prep (candidates + queries) + pack + keep ----------------
// 1024-thr blocks. blk 0..7: per-n candidate bucket sort by |c|^2 -> cFs/ord/sg.
// blk 8..31: pack w1+w2. blk 32..79: keep_coords. blk 80..87: per-n QUERY sort
// by |q|^2 -> qsrt[n][2048] (u16 i), so knn blocks get norm-adjacent queries.
__global__ __launch_bounds__(1024) void prep_sort_k(const float* __restrict__ coords,
                                                    const int* __restrict__ keep,
                                                    const float* __restrict__ w1,
                                                    const float* __restrict__ w2,
                                                    float4* __restrict__ cFs,
                                                    ushort* __restrict__ ord,
                                                    float2* __restrict__ sg,
                                                    float* __restrict__ out0,
                                                    ushort* __restrict__ pw1,
                                                    ushort* __restrict__ pw2,
                                                    ushort* __restrict__ qsrt){
  int blk = blockIdx.x;
  int tid = threadIdx.x;
  if (blk >= 8 && blk < 80){
    if (blk < 32){
      int e = (blk - 8) * 1024 + tid;          // e < 24576
      if (e < 8192) pw1[e] = f2b(w1[e]);
      else          pw2[e - 8192] = f2b(w2[e - 8192]);
    } else {
      int t = (blk - 32) * 1024 + tid;         // t < 49152 = L2*N*3
      int i = t / 24; int rem = t - i * 24;
      out0[t] = coords[(size_t)keep[i] * 24 + rem];
    }
    return;
  }

  __shared__ uint hist[4096];                  // 16 KB
  __shared__ uint wtot[16];
  __shared__ uint gmn[16], gmx[16];
  int lane = tid & 63, wv = tid >> 6;

  if (blk >= 80){
    // ---- query sort: n = blk-80; 2 queries/thread ----
    int n = blk - 80;
    float qc[2]; uint qb[2];
    #pragma unroll
    for (int k = 0; k < 2; ++k){
      int i = tid + (k << 10);
      const float* cr = coords + ((size_t)keep[i] * 8 + n) * 3;
      float x = cr[0], y = cr[1], z = cr[2];
      {
        #pragma clang fp contract(off)
        qc[k] = x*x + y*y + z*z;
      }
    }
    #pragma unroll
    for (int j = 0; j < 4; ++j) hist[tid * 4 + j] = 0;
    __syncthreads();
    #pragma unroll
    for (int k = 0; k < 2; ++k){
      qb[k] = min(4095u, (uint)(qc[k] * 91.0f));
      atomicAdd(&hist[qb[k]], 1u);
    }
    __syncthreads();
    uint c0 = hist[tid*4], c1 = hist[tid*4+1], c2 = hist[tid*4+2], c3 = hist[tid*4+3];
    uint s = c0 + c1 + c2 + c3;
    uint incl = s;
    #pragma unroll
    for (int o = 1; o < 64; o <<= 1){
      uint v = (uint)__shfl_up((int)incl, o, 64);
      if (lane >= o) incl += v;
    }
    if (lane == 63) wtot[wv] = incl;
    __syncthreads();
    uint wbase = 0;
    for (int w = 0; w < wv; ++w) wbase += wtot[w];
    uint base0 = wbase + incl - s;
    __syncthreads();
    hist[tid*4+0] = base0;
    hist[tid*4+1] = base0 + c0;
    hist[tid*4+2] = base0 + c0 + c1;
    hist[tid*4+3] = base0 + c0 + c1 + c2;
    __syncthreads();
    #pragma unroll
    for (int k = 0; k < 2; ++k){
      uint pos = atomicAdd(&hist[qb[k]], 1u);
      qsrt[(n << 11) + pos] = (ushort)(tid + (k << 10));
    }
    return;
  }

  // ---- candidate sort: n = blk ----
  int n = blk;
  float xs[8], ys[8], zs[8], cs[8];
  #pragma unroll
  for (int k = 0; k < 8; ++k){
    int l = tid + (k << 10);
    const float* cr = coords + ((size_t)l * 8 + n) * 3;
    xs[k] = cr[0]; ys[k] = cr[1]; zs[k] = cr[2];
    {
      #pragma clang fp contract(off)
      cs[k] = xs[k]*xs[k] + ys[k]*ys[k] + zs[k]*zs[k];
    }
  }
  #pragma unroll
  for (int j = 0; j < 4; ++j) hist[tid * 4 + j] = 0;
  __syncthreads();
  uint bk[8];
  #pragma unroll
  for (int k = 0; k < 8; ++k){
    bk[k] = min(4095u, (uint)(cs[k] * 91.0f));
    atomicAdd(&hist[bk[k]], 1u);
  }
  __syncthreads();
  uint c0 = hist[tid*4], c1 = hist[tid*4+1], c2 = hist[tid*4+2], c3 = hist[tid*4+3];
  uint s = c0 + c1 + c2 + c3;
  uint incl = s;
  #pragma unroll
  for (int o = 1; o < 64; o <<= 1){
    uint v = (uint)__shfl_up((int)incl, o, 64);
    if (lane >= o) incl += v;
  }
  if (lane == 63) wtot[wv] = incl;
  __syncthreads();
  uint wbase = 0;
  for (int w = 0; w < wv; ++w) wbase += wtot[w];
  uint base0 = wbase + incl - s;
  __syncthreads();
  hist[tid*4+0] = base0;
  hist[tid*4+1] = base0 + c0;
  hist[tid*4+2] = base0 + c0 + c1;
  hist[tid*4+3] = base0 + c0 + c1 + c2;
  __syncthreads();
  #pragma unroll
  for (int k = 0; k < 8; ++k){
    uint pos = atomicAdd(&hist[bk[k]], 1u);
    cFs[((size_t)n << 13) + pos] = make_float4(xs[k], ys[k], zs[k], cs[k]);
    ord[(n << 13) + pos] = (ushort)(tid + (k << 10));
  }
  __syncthreads();
  {
    uint mn = 0xFFFFFFFFu, mx = 0u;
    #pragma unroll
    for (int j = 0; j < 8; ++j){
      int e = ((tid >> 3) << 6) + ((tid & 7) << 3) + j;
      uint u = __float_as_uint(cFs[((size_t)n << 13) + e].w);
      mn = min(mn, u); mx = max(mx, u);
    }
    #pragma unroll
    for (int o = 1; o < 64; o <<= 1){
      mn = min(mn, (uint)__shfl_xor((int)mn, o, 64));
      mx = max(mx, (uint)__shfl_xor((int)mx, o, 64));
    }
    if (lane == 0){ gmn[wv] = mn; gmx[wv] = mx; }
  }
  __syncthreads();
  if (tid < 16)
    sg[n * 16 + tid] = make_float2(sqrtf(__uint_as_float(gmn[tid])),
                                   sqrtf(__uint_as_float(gmx[tid])));
}

// ---------------- K2: MFMA MLP (pre-packed bf16 weights) — R14-identical ----------------
__global__ __launch_bounds__(256) void mlp_k(const float* __restrict__ feat,
                                             const ushort* __restrict__ pw1,
                                             const float* __restrict__ g1,
                                             const float* __restrict__ b1,
                                             const ushort* __restrict__ pw2,
                                             const float* __restrict__ g2,
                                             const float* __restrict__ b2,
                                             uint* __restrict__ fBw){
  __shared__ ushort hlds[64 * 136];
  int tid = threadIdx.x;
  int lane = tid & 63;
  int wv = __builtin_amdgcn_readfirstlane(tid >> 6);
  int quad = lane >> 4, c = lane & 15;
  int rowg = blockIdx.x * 64 + wv * 16;

  bh8 a1[2];
  {
    int rg = rowg + c; int l = rg & 2047, nb = rg >> 11;
    const float* xr = feat + (size_t)((l << 3) + nb) * 64 + quad * 8;
    float t[8];
    ld8(t, xr);      a1[0] = pack8(t);
    ld8(t, xr + 32); a1[1] = pack8(t);
  }

  f32x4 acc1[8];
  #pragma unroll
  for (int t = 0; t < 8; ++t) acc1[t] = (f32x4){0.f, 0.f, 0.f, 0.f};
  #pragma unroll
  for (int s = 0; s < 2; ++s){
    #pragma unroll
    for (int t = 0; t < 8; ++t){
      bh8 wb = *(const bh8*)(pw1 + (size_t)(t * 16 + c) * 64 + s * 32 + quad * 8);
      acc1[t] = __builtin_amdgcn_mfma_f32_16x16x32_bf16(a1[s], wb, acc1[t], 0, 0, 0);
    }
  }

  float mean1[4], rstd1[4];
  #pragma unroll
  for (int r = 0; r < 4; ++r){
    float s = 0.f;
    #pragma unroll
    for (int t = 0; t < 8; ++t) s += acc1[t][r];
    #pragma unroll
    for (int m = 1; m < 16; m <<= 1) s += __shfl_xor(s, m, 16);
    mean1[r] = s * 0.0078125f;
  }
  #pragma unroll
  for (int r = 0; r < 4; ++r){
    float s = 0.f;
    #pragma unroll
    for (int t = 0; t < 8; ++t){ float d = acc1[t][r] - mean1[r]; s += d * d; }
    #pragma unroll
    for (int m = 1; m < 16; m <<= 1) s += __shfl_xor(s, m, 16);
    rstd1[r] = rsqrtf(s * 0.0078125f + 1e-5f);
  }
  ushort* hl = hlds + wv * 16 * 136;
  #pragma unroll
  for (int t = 0; t < 8; ++t){
    float gv = g1[t * 16 + c], bv = b1[t * 16 + c];
    #pragma unroll
    for (int r = 0; r < 4; ++r){
      float v = (acc1[t][r] - mean1[r]) * rstd1[r] * gv + bv;
      hl[(quad * 4 + r) * 136 + t * 16 + c] = f2b(v);
    }
  }

  f32x4 acc2[8];
  #pragma unroll
  for (int t = 0; t < 8; ++t) acc2[t] = (f32x4){0.f, 0.f, 0.f, 0.f};
  #pragma unroll
  for (int s = 0; s < 4; ++s){
    bh8 af = *(const bh8*)(hl + c * 136 + s * 32 + quad * 8);
    #pragma unroll
    for (int t = 0; t < 8; ++t){
      bh8 wb = *(const bh8*)(pw2 + (size_t)(t * 16 + c) * 128 + s * 32 + quad * 8);
      acc2[t] = __builtin_amdgcn_mfma_f32_16x16x32_bf16(af, wb, acc2[t], 0, 0, 0);
    }
  }

  float mean2[4], rstd2[4];
  #pragma unroll
  for (int r = 0; r < 4; ++r){
    float s = 0.f;
    #pragma unroll
    for (int t = 0; t < 8; ++t) s += acc2[t][r];
    #pragma unroll
    for (int m = 1; m < 16; m <<= 1) s += __shfl_xor(s, m, 16);
    mean2[r] = s * 0.0078125f;
  }
  #pragma unroll
  for (int r = 0; r < 4; ++r){
    float s = 0.f;
    #pragma unroll
    for (int t = 0; t < 8; ++t){ float d = acc2[t][r] - mean2[r]; s += d * d; }
    #pragma unroll
    for (int m = 1; m < 16; m <<= 1) s += __shfl_xor(s, m, 16);
    rstd2[r] = rsqrtf(s * 0.0078125f + 1e-5f);
  }
  #pragma unroll
  for (int t = 0; t < 8; ++t){
    float gv = g2[t * 16 + c], bv = b2[t * 16 + c];
    #pragma unroll
    for (int r = 0; r < 4; ++r){
      float v = fmaxf((acc2[t][r] - mean2[r]) * rstd2[r] * gv + bv, 0.f);
      hl[(quad * 4 + r) * 136 + t * 16 + c] = f2b(v);
    }
  }
  {
    int row16 = lane >> 2, chunk = lane & 3;
    const uint* src = (const uint*)hlds + (wv * 16 + row16) * 68 + chunk * 16;
    uint* dst = fBw + (size_t)(rowg + row16) * 64 + chunk * 16;
    #pragma unroll
    for (int j = 0; j < 4; ++j)
      *(uint4*)(dst + j * 4) = *(const uint4*)(src + j * 4);
  }
}

// ---------------- K3: fused KNN + pool; norm-sorted queries + uniform spiral ----------------
__device__ __forceinline__ u64 shfl64(u64 v, int src){
  int lo = __shfl((int)(uint)v, src, 64);
  int hi = __shfl((int)(uint)(v >> 32), src, 64);
  return ((u64)(uint)hi << 32) | (uint)lo;
}

__device__ __forceinline__ u64 bsort64(u64 key, int lane){
  #pragma unroll
  for (int k = 2; k <= 64; k <<= 1){
    #pragma unroll
    for (int j = k >> 1; j > 0; j >>= 1){
      u64 o = shfl64(key, lane ^ j);
      bool lower = (lane & j) == 0;
      bool down  = (lane & k) == 0;
      bool takeMin = (lower == down);
      bool oLess = o < key;
      key = (oLess == takeMin) ? o : key;
    }
  }
  return key;
}
__device__ __forceinline__ u64 bmerge64(u64 key, int lane){
  #pragma unroll
  for (int j = 32; j > 0; j >>= 1){
    u64 o = shfl64(key, lane ^ j);
    bool lower = (lane & j) == 0;
    bool oLess = o < key;
    key = (oLess == lower) ? o : key;
  }
  return key;
}

__device__ __forceinline__ u64 drain(u64* ldsq, int& qcount, float& hf, int lane){
  u64 a = (lane < qcount) ? ldsq[lane] : ~0ull;
  a = bsort64(a, lane);
  if (qcount > 64){
    u64 b = (64 + lane < qcount) ? ldsq[64 + lane] : ~0ull;
    b = bsort64(b, lane);
    u64 br = shfl64(b, 63 - lane);
    a = a < br ? a : br;
    a = bmerge64(a, lane);
  }
  if (lane < 16) ldsq[lane] = a;
  u64 h = shfl64(a, 15);
  hf = unford((uint)(h >> 32));
  qcount = 16;
  return a;
}

__global__ __launch_bounds__(256) void knn_pool_k(const float4* __restrict__ cFs,
                                                  const ushort* __restrict__ ord,
                                                  const float2* __restrict__ sg,
                                                  const ushort* __restrict__ qsrt,
                                                  const float* __restrict__ coords,
                                                  const int* __restrict__ keep,
                                                  const uint* __restrict__ fB32,
                                                  float* __restrict__ out1){
  __shared__ u64 q8[4][2][128];
  int tid = threadIdx.x, lane = tid & 63;
  int wv = tid >> 6;
  int p0 = blockIdx.x * 8 + wv * 2;     // sorted-position; block = 8 norm-adjacent queries
  int n = p0 >> 11;
  int i0 = (int)qsrt[(n << 11) + (p0 & 2047)];
  int i1 = (int)qsrt[(n << 11) + (p0 & 2047) + 1];
  u64* qlA = q8[wv][0];
  u64* qlB = q8[wv][1];
  float4 qa, qb;
  {
    const float* c0p = coords + ((size_t)keep[i0] * 8 + n) * 3;
    const float* c1p = coords + ((size_t)keep[i1] * 8 + n) * 3;
    qa.x = c0p[0]; qa.y = c0p[1]; qa.z = c0p[2];
    qb.x = c1p[0]; qb.y = c1p[1]; qb.z = c1p[2];
    {
      #pragma clang fp contract(off)
      qa.w = qa.x*qa.x + qa.y*qa.y + qa.z*qa.z;
    }
    {
      #pragma clang fp contract(off)
      qb.w = qb.x*qb.x + qb.y*qb.y + qb.z*qb.z;
    }
  }
  float skA = sqrtf(qa.w), skB = sqrtf(qb.w);
  const float4* base = cFs + ((size_t)n << 13);
  const ushort* ordn = ord + (n << 13);
  const float2* sgn = sg + n * 16;

  float hfA = 3.4e38f, hfrA = 3.4e38f; int qcA = 0;
  float hfB = 3.4e38f, hfrB = 3.4e38f; int qcB = 0;

  #define PROCQ(q, hfr, hf, qc, ql, e, jidx, cf) { \
    if (__ballot(e <= hfr)){ \
      u64 bal = __ballot(e <= hfr); \
      if (e <= hfr){ \
        float d2; \
        { \
          _Pragma("clang fp contract(off)") \
          float dot = q.x*(cf).x + q.y*(cf).y + q.z*(cf).z; \
          d2 = (q.w + (cf).w) - 2.0f * dot; \
        } \
        uint ol = (uint)ordn[jidx]; \
        int rel = __builtin_amdgcn_mbcnt_lo((uint)bal, 0); \
        rel = __builtin_amdgcn_mbcnt_hi((uint)(bal >> 32), rel); \
        ql[qc + rel] = ((u64)ford(d2) << 32) | ol; \
      } \
      qc += __popcll(bal); \
      if (qc >= 49){ drain(ql, qc, hf, lane); hfr = hf + 1e-3f; } \
    } \
  }
  // coarse ballot gates the two fine passes (most batches have no survivors)
  #define PROC2(cf, jidx) { \
    float dA = __builtin_fmaf(qa.x,(cf).x, __builtin_fmaf(qa.y,(cf).y, qa.z*(cf).z)); \
    float dB = __builtin_fmaf(qb.x,(cf).x, __builtin_fmaf(qb.y,(cf).y, qb.z*(cf).z)); \
    float eA = __builtin_fmaf(-2.0f, dA, qa.w + (cf).w); \
    float eB = __builtin_fmaf(-2.0f, dB, qb.w + (cf).w); \
    if (__ballot(fminf(eA, eB) <= fmaxf(hfrA, hfrB))){ \
      PROCQ(qa, hfrA, hfA, qcA, qlA, eA, jidx, cf) \
      PROCQ(qb, hfrB, hfB, qcB, qlB, eB, jidx, cf) \
    } \
  }

  // spiral over 16 norm-groups from the queries' shell (block-uniform by qsort)
  int gstart = 0;
  {
    float skM = 0.5f * (skA + skB);
    #pragma unroll
    for (int g = 1; g < 16; ++g) if (sgn[g].x <= skM) gstart = g;
  }
  for (int step = 0; step < 31; ++step){
    int off = (step + 1) >> 1;
    int g = (step & 1) ? gstart - off : gstart + off;
    if (g < 0 || g > 15) continue;
    float2 sv = sgn[g];
    float la = fmaxf(fmaxf(sv.x - skA, skA - sv.y), 0.f);
    float lb = fmaxf(fmaxf(sv.x - skB, skB - sv.y), 0.f);
    if (la * la > hfA + 0.01f && lb * lb > hfB + 0.01f) continue;  // provably safe skip
    const float4* p0v = base + (g << 9);
    #pragma unroll
    for (int half = 0; half < 2; ++half){
      const float4* p = p0v + (half << 8) + lane;
      float4 c0 = p[0];
      float4 c1 = p[64];
      float4 c2 = p[128];
      float4 c3 = p[192];
      int j0 = (g << 9) + (half << 8) + lane;
      PROC2(c0, j0);
      PROC2(c1, j0 + 64);
      PROC2(c2, j0 + 128);
      PROC2(c3, j0 + 192);
    }
  }
  u64 aA = drain(qlA, qcA, hfA, lane);
  u64 aB = drain(qlB, qcB, hfB, lane);
  #undef PROC2
  #undef PROCQ

  const uint* frow = fB32 + ((size_t)(n << 11) << 6);
  float a0 = -3.4e38f, a1v = -3.4e38f, b0 = -3.4e38f, b1v = -3.4e38f;
  #pragma unroll
  for (int k = 0; k < 16; ++k){
    int idxA = (int)(shfl64(aA, k) & 2047u);            // fmod(L2) quirk
    int idxB = (int)(shfl64(aB, k) & 2047u);
    uint uA = frow[((size_t)idxA << 6) + lane];
    uint uB = frow[((size_t)idxB << 6) + lane];
    a0  = fmaxf(a0,  __uint_as_float((uA & 0xFFFFu) << 16));
    a1v = fmaxf(a1v, __uint_as_float((uA >> 16) << 16));
    b0  = fmaxf(b0,  __uint_as_float((uB & 0xFFFFu) << 16));
    b1v = fmaxf(b1v, __uint_as_float((uB >> 16) << 16));
  }
  float2* oA = (float2*)(out1 + (size_t)(i0 * 8 + n) * 128);
  float2* oB = (float2*)(out1 + (size_t)(i1 * 8 + n) * 128);
  oA[lane] = make_float2(a0, a1v);
  oB[lane] = make_float2(b0, b1v);
}

extern "C" void kernel_launch(void* const* d_in, const int* in_sizes, int n_in,
                              void* d_out, int out_size, void* d_ws, size_t ws_size,
                              hipStream_t stream){
  const float* coords = (const float*)d_in[0];
  const float* feat   = (const float*)d_in[1];
  const float* w1     = (const float*)d_in[2];
  const float* g1     = (const float*)d_in[3];
  const float* b1     = (const float*)d_in[4];
  const float* w2     = (const float*)d_in[5];
  const float* g2     = (const float*)d_in[6];
  const float* b2     = (const float*)d_in[7];
  const int*   keep   = (const int*)d_in[8];
  float* out0 = (float*)d_out;                    // keep_coords [2048,8,3]
  float* out1 = out0 + 49152;                     // pool_features [2048,8,128]

  char* ws = (char*)d_ws;
  float4* cFs = (float4*)ws;                      // [N][L] sorted f32x4 : 1 MB
  ushort* fB  = (ushort*)(ws + (1 << 20));        // [N][L2][128] bf16 : 4 MB
  ushort* pw1 = (ushort*)(ws + (5 << 20));        // 16 KB packed w1
  ushort* pw2 = pw1 + 8192;                       // 32 KB packed w2
  ushort* ord = (ushort*)(ws + (5 << 20) + (64 << 10));   // [N][L] u16 : 128 KB
  float2* sg  = (float2*)(ws + (5 << 20) + (256 << 10));  // [N][16] f32x2 : 1 KB
  ushort* qsrt= (ushort*)(ws + (5 << 20) + (257 << 10));  // [N][L2] u16 : 32 KB

  hipLaunchKernelGGL(prep_sort_k, dim3(88), dim3(1024), 0, stream,
                     coords, keep, w1, w2, cFs, ord, sg, out0, pw1, pw2, qsrt);
  hipLaunchKernelGGL(mlp_k, dim3(256), dim3(256), 0, stream,
                     feat, pw1, g1, b1, pw2, g2, b2, (uint*)fB);
  hipLaunchKernelGGL(knn_pool_k, dim3(2048), dim3(256), 0, stream,
                     cFs, ord, sg, qsrt, coords, keep, (const uint*)fB, out1);
}

// Round 18
// 184.736 us; speedup vs baseline: 1.1954x; 1.0288x over previous
//
#include <hip/hip_runtime.h>
#include <stdint.h>

// Problem constants
#define L_    8192
#define N_    8
#define L2_   2048
#define K_    16

typedef unsigned int uint;
typedef unsigned short ushort;
typedef unsigned long long u64;
typedef __attribute__((ext_vector_type(8))) short bh8;   // 8 bf16 (4 VGPRs)
typedef __attribute__((ext_vector_type(4))) float f32x4; // MFMA C/D

// round-to-nearest-even f32 -> bf16 (monotone)
__device__ __forceinline__ ushort f2b(float f){
  uint u = __float_as_uint(f);
  return (ushort)((u + 0x7FFFu + ((u >> 16) & 1u)) >> 16);
}
// monotone float->uint mapping (handles tiny negative self-distances)
__device__ __forceinline__ uint ford(float f){
  uint u = __float_as_uint(f);
  return u ^ ((uint)((int)u >> 31) | 0x80000000u);
}
// inverse of ford
__device__ __forceinline__ float unford(uint u){
  uint v = (u & 0x80000000u) ? (u ^ 0x80000000u) : ~u;
  return __uint_as_float(v);
}

__device__ __forceinline__ void ld8(float* t, const float* p){
  float4 a = *(const float4*)p; float4 b = *(const float4*)(p + 4);
  t[0]=a.x; t[1]=a.y; t[2]=a.z; t[3]=a.w; t[4]=b.x; t[5]=b.y; t[6]=b.z; t[7]=b.w;
}
__device__ __forceinline__ bh8 pack8(const float* v){
  bh8 r;
  #pragma unroll
  for (int j = 0; j < 8; ++j) r[j] = (short)f2b(v[j]);
  return r;
}

// ---------------- K1: norm-sort prep (candidates + queries) + pack + keep ----------------
// 1024-thr blocks. blk 0..7: per-n candidate bucket sort by |c|^2 -> cFs/ord/sg
//   (cc values mirrored to LDS so the group-min/max pass never re-reads global).
// blk 8..31: pack w1+w2. blk 32..79: keep_coords. blk 80..87: per-n query sort.
__global__ __launch_bounds__(1024) void prep_sort_k(const float* __restrict__ coords,
                                                    const int* __restrict__ keep,
                                                    const float* __restrict__ w1,
                                                    const float* __restrict__ w2,
                                                    float4* __restrict__ cFs,
                                                    ushort* __restrict__ ord,
                                                    float2* __restrict__ sg,
                                                    float* __restrict__ out0,
                                                    ushort* __restrict__ pw1,
                                                    ushort* __restrict__ pw2,
                                                    ushort* __restrict__ qsrt){
  int blk = blockIdx.x;
  int tid = threadIdx.x;
  if (blk >= 8 && blk < 80){
    if (blk < 32){
      int e = (blk - 8) * 1024 + tid;          // e < 24576
      if (e < 8192) pw1[e] = f2b(w1[e]);
      else          pw2[e - 8192] = f2b(w2[e - 8192]);
    } else {
      int t = (blk - 32) * 1024 + tid;         // t < 49152 = L2*N*3
      int i = t / 24; int rem = t - i * 24;
      out0[t] = coords[(size_t)keep[i] * 24 + rem];
    }
    return;
  }

  __shared__ uint hist[4096];                  // 16 KB
  __shared__ float ccs[8192];                  // 32 KB: sorted cc mirror (candidate path)
  __shared__ uint wtot[16];
  __shared__ uint gmn[16], gmx[16];
  int lane = tid & 63, wv = tid >> 6;

  if (blk >= 80){
    // ---- query sort: n = blk-80; 2 queries/thread ----
    int n = blk - 80;
    float qc[2]; uint qb[2];
    #pragma unroll
    for (int k = 0; k < 2; ++k){
      int i = tid + (k << 10);
      const float* cr = coords + ((size_t)keep[i] * 8 + n) * 3;
      float x = cr[0], y = cr[1], z = cr[2];
      {
        #pragma clang fp contract(off)
        qc[k] = x*x + y*y + z*z;
      }
    }
    #pragma unroll
    for (int j = 0; j < 4; ++j) hist[tid * 4 + j] = 0;
    __syncthreads();
    #pragma unroll
    for (int k = 0; k < 2; ++k){
      qb[k] = min(4095u, (uint)(qc[k] * 91.0f));
      atomicAdd(&hist[qb[k]], 1u);
    }
    __syncthreads();
    uint c0 = hist[tid*4], c1 = hist[tid*4+1], c2 = hist[tid*4+2], c3 = hist[tid*4+3];
    uint s = c0 + c1 + c2 + c3;
    uint incl = s;
    #pragma unroll
    for (int o = 1; o < 64; o <<= 1){
      uint v = (uint)__shfl_up((int)incl, o, 64);
      if (lane >= o) incl += v;
    }
    if (lane == 63) wtot[wv] = incl;
    __syncthreads();
    uint wbase = 0;
    for (int w = 0; w < wv; ++w) wbase += wtot[w];
    uint base0 = wbase + incl - s;
    __syncthreads();
    hist[tid*4+0] = base0;
    hist[tid*4+1] = base0 + c0;
    hist[tid*4+2] = base0 + c0 + c1;
    hist[tid*4+3] = base0 + c0 + c1 + c2;
    __syncthreads();
    #pragma unroll
    for (int k = 0; k < 2; ++k){
      uint pos = atomicAdd(&hist[qb[k]], 1u);
      qsrt[(n << 11) + pos] = (ushort)(tid + (k << 10));
    }
    return;
  }

  // ---- candidate sort: n = blk ----
  int n = blk;
  float xs[8], ys[8], zs[8], cs[8];
  #pragma unroll
  for (int k = 0; k < 8; ++k){
    int l = tid + (k << 10);
    const float* cr = coords + ((size_t)l * 8 + n) * 3;
    xs[k] = cr[0]; ys[k] = cr[1]; zs[k] = cr[2];
    {
      #pragma clang fp contract(off)
      cs[k] = xs[k]*xs[k] + ys[k]*ys[k] + zs[k]*zs[k];
    }
  }
  #pragma unroll
  for (int j = 0; j < 4; ++j) hist[tid * 4 + j] = 0;
  __syncthreads();
  uint bk[8];
  #pragma unroll
  for (int k = 0; k < 8; ++k){
    bk[k] = min(4095u, (uint)(cs[k] * 91.0f));
    atomicAdd(&hist[bk[k]], 1u);
  }
  __syncthreads();
  uint c0 = hist[tid*4], c1 = hist[tid*4+1], c2 = hist[tid*4+2], c3 = hist[tid*4+3];
  uint s = c0 + c1 + c2 + c3;
  uint incl = s;
  #pragma unroll
  for (int o = 1; o < 64; o <<= 1){
    uint v = (uint)__shfl_up((int)incl, o, 64);
    if (lane >= o) incl += v;
  }
  if (lane == 63) wtot[wv] = incl;
  __syncthreads();
  uint wbase = 0;
  for (int w = 0; w < wv; ++w) wbase += wtot[w];
  uint base0 = wbase + incl - s;
  __syncthreads();
  hist[tid*4+0] = base0;
  hist[tid*4+1] = base0 + c0;
  hist[tid*4+2] = base0 + c0 + c1;
  hist[tid*4+3] = base0 + c0 + c1 + c2;
  __syncthreads();
  #pragma unroll
  for (int k = 0; k < 8; ++k){
    uint pos = atomicAdd(&hist[bk[k]], 1u);
    cFs[((size_t)n << 13) + pos] = make_float4(xs[k], ys[k], zs[k], cs[k]);
    ord[(n << 13) + pos] = (ushort)(tid + (k << 10));
    ccs[pos] = cs[k];                          // LDS mirror for the min/max pass
  }
  __syncthreads();
  {
    uint mn = 0xFFFFFFFFu, mx = 0u;
    #pragma unroll
    for (int j = 0; j < 8; ++j){
      int e = ((tid >> 3) << 6) + ((tid & 7) << 3) + j;   // e in [wv*512, wv*512+512)
      uint u = __float_as_uint(ccs[e]);        // cc >= 0: bits monotone
      mn = min(mn, u); mx = max(mx, u);
    }
    #pragma unroll
    for (int o = 1; o < 64; o <<= 1){
      mn = min(mn, (uint)__shfl_xor((int)mn, o, 64));
      mx = max(mx, (uint)__shfl_xor((int)mx, o, 64));
    }
    if (lane == 0){ gmn[wv] = mn; gmx[wv] = mx; }
  }
  __syncthreads();
  if (tid < 16)
    sg[n * 16 + tid] = make_float2(sqrtf(__uint_as_float(gmn[tid])),
                                   sqrtf(__uint_as_float(gmx[tid])));
}

// ---------------- K2: MFMA MLP (pre-packed bf16 weights) — R14-identical ----------------
__global__ __launch_bounds__(256) void mlp_k(const float* __restrict__ feat,
                                             const ushort* __restrict__ pw1,
                                             const float* __restrict__ g1,
                                             const float* __restrict__ b1,
                                             const ushort* __restrict__ pw2,
                                             const float* __restrict__ g2,
                                             const float* __restrict__ b2,
                                             uint* __restrict__ fBw){
  __shared__ ushort hlds[64 * 136];
  int tid = threadIdx.x;
  int lane = tid & 63;
  int wv = __builtin_amdgcn_readfirstlane(tid >> 6);
  int quad = lane >> 4, c = lane & 15;
  int rowg = blockIdx.x * 64 + wv * 16;

  bh8 a1[2];
  {
    int rg = rowg + c; int l = rg & 2047, nb = rg >> 11;
    const float* xr = feat + (size_t)((l << 3) + nb) * 64 + quad * 8;
    float t[8];
    ld8(t, xr);      a1[0] = pack8(t);
    ld8(t, xr + 32); a1[1] = pack8(t);
  }

  f32x4 acc1[8];
  #pragma unroll
  for (int t = 0; t < 8; ++t) acc1[t] = (f32x4){0.f, 0.f, 0.f, 0.f};
  #pragma unroll
  for (int s = 0; s < 2; ++s){
    #pragma unroll
    for (int t = 0; t < 8; ++t){
      bh8 wb = *(const bh8*)(pw1 + (size_t)(t * 16 + c) * 64 + s * 32 + quad * 8);
      acc1[t] = __builtin_amdgcn_mfma_f32_16x16x32_bf16(a1[s], wb, acc1[t], 0, 0, 0);
    }
  }

  float mean1[4], rstd1[4];
  #pragma unroll
  for (int r = 0; r < 4; ++r){
    float s = 0.f;
    #pragma unroll
    for (int t = 0; t < 8; ++t) s += acc1[t][r];
    #pragma unroll
    for (int m = 1; m < 16; m <<= 1) s += __shfl_xor(s, m, 16);
    mean1[r] = s * 0.0078125f;
  }
  #pragma unroll
  for (int r = 0; r < 4; ++r){
    float s = 0.f;
    #pragma unroll
    for (int t = 0; t < 8; ++t){ float d = acc1[t][r] - mean1[r]; s += d * d; }
    #pragma unroll
    for (int m = 1; m < 16; m <<= 1) s += __shfl_xor(s, m, 16);
    rstd1[r] = rsqrtf(s * 0.0078125f + 1e-5f);
  }
  ushort* hl = hlds + wv * 16 * 136;
  #pragma unroll
  for (int t = 0; t < 8; ++t){
    float gv = g1[t * 16 + c], bv = b1[t * 16 + c];
    #pragma unroll
    for (int r = 0; r < 4; ++r){
      float v = (acc1[t][r] - mean1[r]) * rstd1[r] * gv + bv;
      hl[(quad * 4 + r) * 136 + t * 16 + c] = f2b(v);
    }
  }

  f32x4 acc2[8];
  #pragma unroll
  for (int t = 0; t < 8; ++t) acc2[t] = (f32x4){0.f, 0.f, 0.f, 0.f};
  #pragma unroll
  for (int s = 0; s < 4; ++s){
    bh8 af = *(const bh8*)(hl + c * 136 + s * 32 + quad * 8);
    #pragma unroll
    for (int t = 0; t < 8; ++t){
      bh8 wb = *(const bh8*)(pw2 + (size_t)(t * 16 + c) * 128 + s * 32 + quad * 8);
      acc2[t] = __builtin_amdgcn_mfma_f32_16x16x32_bf16(af, wb, acc2[t], 0, 0, 0);
    }
  }

  float mean2[4], rstd2[4];
  #pragma unroll
  for (int r = 0; r < 4; ++r){
    float s = 0.f;
    #pragma unroll
    for (int t = 0; t < 8; ++t) s += acc2[t][r];
    #pragma unroll
    for (int m = 1; m < 16; m <<= 1) s += __shfl_xor(s, m, 16);
    mean2[r] = s * 0.0078125f;
  }
  #pragma unroll
  for (int r = 0; r < 4; ++r){
    float s = 0.f;
    #pragma unroll
    for (int t = 0; t < 8; ++t){ float d = acc2[t][r] - mean2[r]; s += d * d; }
    #pragma unroll
    for (int m = 1; m < 16; m <<= 1) s += __shfl_xor(s, m, 16);
    rstd2[r] = rsqrtf(s * 0.0078125f + 1e-5f);
  }
  #pragma unroll
  for (int t = 0; t < 8; ++t){
    float gv = g2[t * 16 + c], bv = b2[t * 16 + c];
    #pragma unroll
    for (int r = 0; r < 4; ++r){
      float v = fmaxf((acc2[t][r] - mean2[r]) * rstd2[r] * gv + bv, 0.f);
      hl[(quad * 4 + r) * 136 + t * 16 + c] = f2b(v);
    }
  }
  {
    int row16 = lane >> 2, chunk = lane & 3;
    const uint* src = (const uint*)hlds + (wv * 16 + row16) * 68 + chunk * 16;
    uint* dst = fBw + (size_t)(rowg + row16) * 64 + chunk * 16;
    #pragma unroll
    for (int j = 0; j < 4; ++j)
      *(uint4*)(dst + j * 4) = *(const uint4*)(src + j * 4);
  }
}

// ---------------- K3: fused KNN + pool; qsort-uniform spiral, 8-deep group pipeline ----------------
__device__ __forceinline__ u64 shfl64(u64 v, int src){
  int lo = __shfl((int)(uint)v, src, 64);
  int hi = __shfl((int)(uint)(v >> 32), src, 64);
  return ((u64)(uint)hi << 32) | (uint)lo;
}

__device__ __forceinline__ u64 bsort64(u64 key, int lane){
  #pragma unroll
  for (int k = 2; k <= 64; k <<= 1){
    #pragma unroll
    for (int j = k >> 1; j > 0; j >>= 1){
      u64 o = shfl64(key, lane ^ j);
      bool lower = (lane & j) == 0;
      bool down  = (lane & k) == 0;
      bool takeMin = (lower == down);
      bool oLess = o < key;
      key = (oLess == takeMin) ? o : key;
    }
  }
  return key;
}
__device__ __forceinline__ u64 bmerge64(u64 key, int lane){
  #pragma unroll
  for (int j = 32; j > 0; j >>= 1){
    u64 o = shfl64(key, lane ^ j);
    bool lower = (lane & j) == 0;
    bool oLess = o < key;
    key = (oLess == lower) ? o : key;
  }
  return key;
}

__device__ __forceinline__ u64 drain(u64* ldsq, int& qcount, float& hf, int lane){
  u64 a = (lane < qcount) ? ldsq[lane] : ~0ull;
  a = bsort64(a, lane);
  if (qcount > 64){
    u64 b = (64 + lane < qcount) ? ldsq[64 + lane] : ~0ull;
    b = bsort64(b, lane);
    u64 br = shfl64(b, 63 - lane);
    a = a < br ? a : br;
    a = bmerge64(a, lane);
  }
  if (lane < 16) ldsq[lane] = a;
  u64 h = shfl64(a, 15);
  hf = unford((uint)(h >> 32));
  qcount = 16;
  return a;
}

__global__ __launch_bounds__(256) void knn_pool_k(const float4* __restrict__ cFs,
                                                  const ushort* __restrict__ ord,
                                                  const float2* __restrict__ sg,
                                                  const ushort* __restrict__ qsrt,
                                                  const float* __restrict__ coords,
                                                  const int* __restrict__ keep,
                                                  const uint* __restrict__ fB32,
                                                  float* __restrict__ out1){
  __shared__ u64 q8[4][2][128];
  int tid = threadIdx.x, lane = tid & 63;
  int wv = tid >> 6;
  int p0 = blockIdx.x * 8 + wv * 2;     // sorted-position; block = 8 norm-adjacent queries
  int n = p0 >> 11;
  int i0 = (int)qsrt[(n << 11) + (p0 & 2047)];
  int i1 = (int)qsrt[(n << 11) + (p0 & 2047) + 1];
  u64* qlA = q8[wv][0];
  u64* qlB = q8[wv][1];
  float4 qa, qb;
  {
    const float* c0p = coords + ((size_t)keep[i0] * 8 + n) * 3;
    const float* c1p = coords + ((size_t)keep[i1] * 8 + n) * 3;
    qa.x = c0p[0]; qa.y = c0p[1]; qa.z = c0p[2];
    qb.x = c1p[0]; qb.y = c1p[1]; qb.z = c1p[2];
    {
      #pragma clang fp contract(off)
      qa.w = qa.x*qa.x + qa.y*qa.y + qa.z*qa.z;
    }
    {
      #pragma clang fp contract(off)
      qb.w = qb.x*qb.x + qb.y*qb.y + qb.z*qb.z;
    }
  }
  float skA = sqrtf(qa.w), skB = sqrtf(qb.w);
  const float4* base = cFs + ((size_t)n << 13);
  const ushort* ordn = ord + (n << 13);
  const float2* sgn = sg + n * 16;

  float hfA = 3.4e38f, hfrA = 3.4e38f; int qcA = 0;
  float hfB = 3.4e38f, hfrB = 3.4e38f; int qcB = 0;

  // single-ballot per query (bal precomputed); drain is exact on (d2, orig idx)
  #define PROCQ(q, hfr, hf, qc, ql, e, bal, jidx, cf) { \
    if (bal){ \
      if (e <= hfr){ \
        float d2; \
        { \
          _Pragma("clang fp contract(off)") \
          float dot = q.x*(cf).x + q.y*(cf).y + q.z*(cf).z; \
          d2 = (q.w + (cf).w) - 2.0f * dot; \
        } \
        uint ol = (uint)ordn[jidx]; \
        int rel = __builtin_amdgcn_mbcnt_lo((uint)bal, 0); \
        rel = __builtin_amdgcn_mbcnt_hi((uint)(bal >> 32), rel); \
        ql[qc + rel] = ((u64)ford(d2) << 32) | ol; \
      } \
      qc += __popcll(bal); \
      if (qc >= 49){ drain(ql, qc, hf, lane); hfr = hf + 1e-3f; } \
    } \
  }
  // coarse ballot gates both fine ballots (most batches have no survivors)
  #define PROC2(cf, jidx) { \
    float dA = __builtin_fmaf(qa.x,(cf).x, __builtin_fmaf(qa.y,(cf).y, qa.z*(cf).z)); \
    float dB = __builtin_fmaf(qb.x,(cf).x, __builtin_fmaf(qb.y,(cf).y, qb.z*(cf).z)); \
    float eA = __builtin_fmaf(-2.0f, dA, qa.w + (cf).w); \
    float eB = __builtin_fmaf(-2.0f, dB, qb.w + (cf).w); \
    if (__ballot(fminf(eA, eB) <= fmaxf(hfrA, hfrB))){ \
      u64 balA = __ballot(eA <= hfrA); \
      u64 balB = __ballot(eB <= hfrB); \
      PROCQ(qa, hfrA, hfA, qcA, qlA, eA, balA, jidx, cf) \
      PROCQ(qb, hfrB, hfB, qcB, qlB, eB, balB, jidx, cf) \
    } \
  }

  // spiral over 16 norm-groups from the queries' shell (block-uniform by qsort)
  int gstart = 0;
  {
    float skM = 0.5f * (skA + skB);
    #pragma unroll
    for (int g = 1; g < 16; ++g) if (sgn[g].x <= skM) gstart = g;
  }
  for (int step = 0; step < 31; ++step){
    int off = (step + 1) >> 1;
    int g = (step & 1) ? gstart - off : gstart + off;
    if (g < 0 || g > 15) continue;
    float2 sv = sgn[g];
    float la = fmaxf(fmaxf(sv.x - skA, skA - sv.y), 0.f);
    float lb = fmaxf(fmaxf(sv.x - skB, skB - sv.y), 0.f);
    if (la * la > hfA + 0.01f && lb * lb > hfB + 0.01f) continue;  // provably safe skip
    // whole 512-candidate group loaded up-front: 8 loads in flight
    const float4* p = base + (g << 9) + lane;
    float4 c0 = p[0];
    float4 c1 = p[64];
    float4 c2 = p[128];
    float4 c3 = p[192];
    float4 c4 = p[256];
    float4 c5 = p[320];
    float4 c6 = p[384];
    float4 c7 = p[448];
    int j0 = (g << 9) + lane;
    PROC2(c0, j0);
    PROC2(c1, j0 + 64);
    PROC2(c2, j0 + 128);
    PROC2(c3, j0 + 192);
    PROC2(c4, j0 + 256);
    PROC2(c5, j0 + 320);
    PROC2(c6, j0 + 384);
    PROC2(c7, j0 + 448);
  }
  u64 aA = drain(qlA, qcA, hfA, lane);
  u64 aB = drain(qlB, qcB, hfB, lane);
  #undef PROC2
  #undef PROCQ

  const uint* frow = fB32 + ((size_t)(n << 11) << 6);
  float a0 = -3.4e38f, a1v = -3.4e38f, b0 = -3.4e38f, b1v = -3.4e38f;
  #pragma unroll
  for (int k = 0; k < 16; ++k){
    int idxA = (int)(shfl64(aA, k) & 2047u);            // fmod(L2) quirk
    int idxB = (int)(shfl64(aB, k) & 2047u);
    uint uA = frow[((size_t)idxA << 6) + lane];
    uint uB = frow[((size_t)idxB << 6) + lane];
    a0  = fmaxf(a0,  __uint_as_float((uA & 0xFFFFu) << 16));
    a1v = fmaxf(a1v, __uint_as_float((uA >> 16) << 16));
    b0  = fmaxf(b0,  __uint_as_float((uB & 0xFFFFu) << 16));
    b1v = fmaxf(b1v, __uint_as_float((uB >> 16) << 16));
  }
  float2* oA = (float2*)(out1 + (size_t)(i0 * 8 + n) * 128);
  float2* oB = (float2*)(out1 + (size_t)(i1 * 8 + n) * 128);
  oA[lane] = make_float2(a0, a1v);
  oB[lane] = make_float2(b0, b1v);
}

extern "C" void kernel_launch(void* const* d_in, const int* in_sizes, int n_in,
                              void* d_out, int out_size, void* d_ws, size_t ws_size,
                              hipStream_t stream){
  const float* coords = (const float*)d_in[0];
  const float* feat   = (const float*)d_in[1];
  const float* w1     = (const float*)d_in[2];
  const float* g1     = (const float*)d_in[3];
  const float* b1     = (const float*)d_in[4];
  const float* w2     = (const float*)d_in[5];
  const float* g2     = (const float*)d_in[6];
  const float* b2     = (const float*)d_in[7];
  const int*   keep   = (const int*)d_in[8];
  float* out0 = (float*)d_out;                    // keep_coords [2048,8,3]
  float* out1 = out0 + 49152;                     // pool_features [2048,8,128]

  char* ws = (char*)d_ws;
  float4* cFs = (float4*)ws;                      // [N][L] sorted f32x4 : 1 MB
  ushort* fB  = (ushort*)(ws + (1 << 20));        // [N][L2][128] bf16 : 4 MB
  ushort* pw1 = (ushort*)(ws + (5 << 20));        // 16 KB packed w1
  ushort* pw2 = pw1 + 8192;                       // 32 KB packed w2
  ushort* ord = (ushort*)(ws + (5 << 20) + (64 << 10));   // [N][L] u16 : 128 KB
  float2* sg  = (float2*)(ws + (5 << 20) + (256 << 10));  // [N][16] f32x2 : 1 KB
  ushort* qsrt= (ushort*)(ws + (5 << 20) + (257 << 10));  // [N][L2] u16 : 32 KB

  hipLaunchKernelGGL(prep_sort_k, dim3(88), dim3(1024), 0, stream,
                     coords, keep, w1, w2, cFs, ord, sg, out0, pw1, pw2, qsrt);
  hipLaunchKernelGGL(mlp_k, dim3(256), dim3(256), 0, stream,
                     feat, pw1, g1, b1, pw2, g2, b2, (uint*)fB);
  hipLaunchKernelGGL(knn_pool_k, dim3(2048), dim3(256), 0, stream,
                     cFs, ord, sg, qsrt, coords, keep, (const uint*)fB, out1);
}

// Round 19
// 183.986 us; speedup vs baseline: 1.2002x; 1.0041x over previous
//
#include <hip/hip_runtime.h>
#include <stdint.h>

// Problem constants
#define L_    8192
#define N_    8
#define L2_   2048
#define K_    16

typedef unsigned int uint;
typedef unsigned short ushort;
typedef unsigned long long u64;
typedef __attribute__((ext_vector_type(8))) short bh8;   // 8 bf16 (4 VGPRs)
typedef __attribute__((ext_vector_type(4))) float f32x4; // MFMA C/D

// round-to-nearest-even f32 -> bf16 (monotone)
__device__ __forceinline__ ushort f2b(float f){
  uint u = __float_as_uint(f);
  return (ushort)((u + 0x7FFFu + ((u >> 16) & 1u)) >> 16);
}
// monotone float->uint mapping (handles tiny negative self-distances)
__device__ __forceinline__ uint ford(float f){
  uint u = __float_as_uint(f);
  return u ^ ((uint)((int)u >> 31) | 0x80000000u);
}
// inverse of ford
__device__ __forceinline__ float unford(uint u){
  uint v = (u & 0x80000000u) ? (u ^ 0x80000000u) : ~u;
  return __uint_as_float(v);
}

__device__ __forceinline__ void ld8(float* t, const float* p){
  float4 a = *(const float4*)p; float4 b = *(const float4*)(p + 4);
  t[0]=a.x; t[1]=a.y; t[2]=a.z; t[3]=a.w; t[4]=b.x; t[5]=b.y; t[6]=b.z; t[7]=b.w;
}
__device__ __forceinline__ bh8 pack8(const float* v){
  bh8 r;
  #pragma unroll
  for (int j = 0; j < 8; ++j) r[j] = (short)f2b(v[j]);
  return r;
}

// ---------------- K0: transpose prep + weight pack + keep_coords (all coalesced) ----------------
// blk [0,96): pack w1+w2. blk [96,352): cT[n][l]={x,y,z,cc}. blk [352,544): keep_coords.
__global__ __launch_bounds__(256) void prep_k(const float* __restrict__ coords,
                                              const int* __restrict__ keep,
                                              const float* __restrict__ w1,
                                              const float* __restrict__ w2,
                                              float4* __restrict__ cT,
                                              float* __restrict__ out0,
                                              ushort* __restrict__ pw1,
                                              ushort* __restrict__ pw2){
  int blk = blockIdx.x;
  int tid = threadIdx.x;
  if (blk < 96){
    int e = blk * 256 + tid;                   // e < 24576
    if (e < 8192) pw1[e] = f2b(w1[e]);
    else          pw2[e - 8192] = f2b(w2[e - 8192]);
  } else if (blk < 352){
    int e = (blk - 96) * 256 + tid;            // e = l*8+n, e < 65536
    int l = e >> 3, n = e & 7;
    const float* cr = coords + (size_t)e * 3;
    float x = cr[0], y = cr[1], z = cr[2];
    float cc;
    {
      #pragma clang fp contract(off)
      cc = x*x + y*y + z*z;                    // matches np sum(c*c,-1): (xx+yy)+zz
    }
    cT[n * L_ + l] = make_float4(x, y, z, cc);
  } else {
    int t = (blk - 352) * 256 + tid;           // t < 49152 = L2*N*3
    int i = t / 24; int rem = t - i * 24;      // (n*3+c)
    out0[t] = coords[(size_t)keep[i] * 24 + rem];
  }
}

// ---------------- K1: MFMA MLP + candidate sort + query sort (one launch) ----------------
// blk [0,256): MLP (R14 body). blk [256,264): per-n candidate bucket sort reading cT
// coalesced -> cFs/ord/sg. blk [264,272): per-n query sort -> qsrt.
__global__ __launch_bounds__(256) void mid_k(const float* __restrict__ feat,
                                             const ushort* __restrict__ pw1,
                                             const float* __restrict__ g1,
                                             const float* __restrict__ b1,
                                             const ushort* __restrict__ pw2,
                                             const float* __restrict__ g2,
                                             const float* __restrict__ b2,
                                             uint* __restrict__ fBw,
                                             const float4* __restrict__ cT,
                                             const int* __restrict__ keep,
                                             float4* __restrict__ cFs,
                                             ushort* __restrict__ ord,
                                             float2* __restrict__ sg,
                                             ushort* __restrict__ qsrt){
  int blk = blockIdx.x;
  int tid = threadIdx.x;
  int lane = tid & 63;

  if (blk >= 256){
    __shared__ uint hist[4096];                // 16 KB
    __shared__ float ccs[8192];                // 32 KB (candidate path only)
    __shared__ uint wtot[4];
    __shared__ uint gmn[16], gmx[16];
    int wv = tid >> 6;

    if (blk < 264){
      // ---- candidate sort, n = blk-256; 32 elems/thread, coalesced cT reads ----
      int n = blk - 256;
      const float4* src = cT + ((size_t)n << 13);
      #pragma unroll
      for (int j = 0; j < 16; ++j) hist[tid * 16 + j] = 0;
      if (tid < 16){ gmn[tid] = 0xFFFFFFFFu; gmx[tid] = 0u; }
      __syncthreads();
      // pass 1: histogram (cc re-read in pass 2; stays in L1/L2)
      for (int k = 0; k < 32; ++k){
        float cc = src[tid + (k << 8)].w;
        uint b = min(4095u, (uint)(cc * 91.0f));
        atomicAdd(&hist[b], 1u);
      }
      __syncthreads();
      // exclusive scan over 4096 buckets (thread owns 16)
      uint c[16]; uint s = 0;
      #pragma unroll
      for (int j = 0; j < 16; ++j){ c[j] = hist[tid * 16 + j]; s += c[j]; }
      uint incl = s;
      #pragma unroll
      for (int o = 1; o < 64; o <<= 1){
        uint v = (uint)__shfl_up((int)incl, o, 64);
        if (lane >= o) incl += v;
      }
      if (lane == 63) wtot[wv] = incl;
      __syncthreads();
      uint wbase = 0;
      for (int w = 0; w < wv; ++w) wbase += wtot[w];
      uint run = wbase + incl - s;
      __syncthreads();
      #pragma unroll
      for (int j = 0; j < 16; ++j){ hist[tid * 16 + j] = run; run += c[j]; }
      __syncthreads();
      // pass 2: scatter
      for (int k = 0; k < 32; ++k){
        int e = tid + (k << 8);
        float4 v = src[e];
        uint b = min(4095u, (uint)(v.w * 91.0f));
        uint pos = atomicAdd(&hist[b], 1u);
        cFs[((size_t)n << 13) + pos] = v;
        ord[(n << 13) + pos] = (ushort)e;
        ccs[pos] = v.w;
      }
      __syncthreads();
      // per-512-group min/max from LDS mirror (thread covers 32 contiguous, one group)
      {
        uint mn = 0xFFFFFFFFu, mx = 0u;
        int e0 = tid * 32;
        #pragma unroll
        for (int j = 0; j < 32; ++j){
          uint u = __float_as_uint(ccs[e0 + j]);   // cc >= 0: bits monotone
          mn = min(mn, u); mx = max(mx, u);
        }
        int g = tid >> 4;                          // = e0 / 512
        atomicMin(&gmn[g], mn);
        atomicMax(&gmx[g], mx);
      }
      __syncthreads();
      if (tid < 16)
        sg[n * 16 + tid] = make_float2(sqrtf(__uint_as_float(gmn[tid])),
                                       sqrtf(__uint_as_float(gmx[tid])));
    } else {
      // ---- query sort, n = blk-264; 8 queries/thread ----
      int n = blk - 264;
      const float4* src = cT + ((size_t)n << 13);
      #pragma unroll
      for (int j = 0; j < 16; ++j) hist[tid * 16 + j] = 0;
      __syncthreads();
      float qc[8];
      #pragma unroll
      for (int k = 0; k < 8; ++k){
        int i = tid + (k << 8);
        qc[k] = src[keep[i]].w;
        uint b = min(4095u, (uint)(qc[k] * 91.0f));
        atomicAdd(&hist[b], 1u);
      }
      __syncthreads();
      uint c[16]; uint s = 0;
      #pragma unroll
      for (int j = 0; j < 16; ++j){ c[j] = hist[tid * 16 + j]; s += c[j]; }
      uint incl = s;
      #pragma unroll
      for (int o = 1; o < 64; o <<= 1){
        uint v = (uint)__shfl_up((int)incl, o, 64);
        if (lane >= o) incl += v;
      }
      if (lane == 63) wtot[wv] = incl;
      __syncthreads();
      uint wbase = 0;
      for (int w = 0; w < wv; ++w) wbase += wtot[w];
      uint run = wbase + incl - s;
      __syncthreads();
      #pragma unroll
      for (int j = 0; j < 16; ++j){ hist[tid * 16 + j] = run; run += c[j]; }
      __syncthreads();
      #pragma unroll
      for (int k = 0; k < 8; ++k){
        uint b = min(4095u, (uint)(qc[k] * 91.0f));
        uint pos = atomicAdd(&hist[b], 1u);
        qsrt[(n << 11) + pos] = (ushort)(tid + (k << 8));
      }
    }
    return;
  }

  // ---- MLP (R14 body) ----
  __shared__ ushort hlds[64 * 136];
  int wv = __builtin_amdgcn_readfirstlane(tid >> 6);
  int quad = lane >> 4, c = lane & 15;
  int rowg = blk * 64 + wv * 16;

  bh8 a1[2];
  {
    int rg = rowg + c; int l = rg & 2047, nb = rg >> 11;
    const float* xr = feat + (size_t)((l << 3) + nb) * 64 + quad * 8;
    float t[8];
    ld8(t, xr);      a1[0] = pack8(t);
    ld8(t, xr + 32); a1[1] = pack8(t);
  }

  f32x4 acc1[8];
  #pragma unroll
  for (int t = 0; t < 8; ++t) acc1[t] = (f32x4){0.f, 0.f, 0.f, 0.f};
  #pragma unroll
  for (int s = 0; s < 2; ++s){
    #pragma unroll
    for (int t = 0; t < 8; ++t){
      bh8 wb = *(const bh8*)(pw1 + (size_t)(t * 16 + c) * 64 + s * 32 + quad * 8);
      acc1[t] = __builtin_amdgcn_mfma_f32_16x16x32_bf16(a1[s], wb, acc1[t], 0, 0, 0);
    }
  }

  float mean1[4], rstd1[4];
  #pragma unroll
  for (int r = 0; r < 4; ++r){
    float s = 0.f;
    #pragma unroll
    for (int t = 0; t < 8; ++t) s += acc1[t][r];
    #pragma unroll
    for (int m = 1; m < 16; m <<= 1) s += __shfl_xor(s, m, 16);
    mean1[r] = s * 0.0078125f;
  }
  #pragma unroll
  for (int r = 0; r < 4; ++r){
    float s = 0.f;
    #pragma unroll
    for (int t = 0; t < 8; ++t){ float d = acc1[t][r] - mean1[r]; s += d * d; }
    #pragma unroll
    for (int m = 1; m < 16; m <<= 1) s += __shfl_xor(s, m, 16);
    rstd1[r] = rsqrtf(s * 0.0078125f + 1e-5f);
  }
  ushort* hl = hlds + wv * 16 * 136;
  #pragma unroll
  for (int t = 0; t < 8; ++t){
    float gv = g1[t * 16 + c], bv = b1[t * 16 + c];
    #pragma unroll
    for (int r = 0; r < 4; ++r){
      float v = (acc1[t][r] - mean1[r]) * rstd1[r] * gv + bv;
      hl[(quad * 4 + r) * 136 + t * 16 + c] = f2b(v);
    }
  }

  f32x4 acc2[8];
  #pragma unroll
  for (int t = 0; t < 8; ++t) acc2[t] = (f32x4){0.f, 0.f, 0.f, 0.f};
  #pragma unroll
  for (int s = 0; s < 4; ++s){
    bh8 af = *(const bh8*)(hl + c * 136 + s * 32 + quad * 8);
    #pragma unroll
    for (int t = 0; t < 8; ++t){
      bh8 wb = *(const bh8*)(pw2 + (size_t)(t * 16 + c) * 128 + s * 32 + quad * 8);
      acc2[t] = __builtin_amdgcn_mfma_f32_16x16x32_bf16(af, wb, acc2[t], 0, 0, 0);
    }
  }

  float mean2[4], rstd2[4];
  #pragma unroll
  for (int r = 0; r < 4; ++r){
    float s = 0.f;
    #pragma unroll
    for (int t = 0; t < 8; ++t) s += acc2[t][r];
    #pragma unroll
    for (int m = 1; m < 16; m <<= 1) s += __shfl_xor(s, m, 16);
    mean2[r] = s * 0.0078125f;
  }
  #pragma unroll
  for (int r = 0; r < 4; ++r){
    float s = 0.f;
    #pragma unroll
    for (int t = 0; t < 8; ++t){ float d = acc2[t][r] - mean2[r]; s += d * d; }
    #pragma unroll
    for (int m = 1; m < 16; m <<= 1) s += __shfl_xor(s, m, 16);
    rstd2[r] = rsqrtf(s * 0.0078125f + 1e-5f);
  }
  #pragma unroll
  for (int t = 0; t < 8; ++t){
    float gv = g2[t * 16 + c], bv = b2[t * 16 + c];
    #pragma unroll
    for (int r = 0; r < 4; ++r){
      float v = fmaxf((acc2[t][r] - mean2[r]) * rstd2[r] * gv + bv, 0.f);
      hl[(quad * 4 + r) * 136 + t * 16 + c] = f2b(v);
    }
  }
  {
    int row16 = lane >> 2, chunk = lane & 3;
    const uint* src = (const uint*)hlds + (wv * 16 + row16) * 68 + chunk * 16;
    uint* dst = fBw + (size_t)(rowg + row16) * 64 + chunk * 16;
    #pragma unroll
    for (int j = 0; j < 4; ++j)
      *(uint4*)(dst + j * 4) = *(const uint4*)(src + j * 4);
  }
}

// ---------------- K2: fused KNN + pool (R18-identical) ----------------
__device__ __forceinline__ u64 shfl64(u64 v, int src){
  int lo = __shfl((int)(uint)v, src, 64);
  int hi = __shfl((int)(uint)(v >> 32), src, 64);
  return ((u64)(uint)hi << 32) | (uint)lo;
}

__device__ __forceinline__ u64 bsort64(u64 key, int lane){
  #pragma unroll
  for (int k = 2; k <= 64; k <<= 1){
    #pragma unroll
    for (int j = k >> 1; j > 0; j >>= 1){
      u64 o = shfl64(key, lane ^ j);
      bool lower = (lane & j) == 0;
      bool down  = (lane & k) == 0;
      bool takeMin = (lower == down);
      bool oLess = o < key;
      key = (oLess == takeMin) ? o : key;
    }
  }
  return key;
}
__device__ __forceinline__ u64 bmerge64(u64 key, int lane){
  #pragma unroll
  for (int j = 32; j > 0; j >>= 1){
    u64 o = shfl64(key, lane ^ j);
    bool lower = (lane & j) == 0;
    bool oLess = o < key;
    key = (oLess == lower) ? o : key;
  }
  return key;
}

__device__ __forceinline__ u64 drain(u64* ldsq, int& qcount, float& hf, int lane){
  u64 a = (lane < qcount) ? ldsq[lane] : ~0ull;
  a = bsort64(a, lane);
  if (qcount > 64){
    u64 b = (64 + lane < qcount) ? ldsq[64 + lane] : ~0ull;
    b = bsort64(b, lane);
    u64 br = shfl64(b, 63 - lane);
    a = a < br ? a : br;
    a = bmerge64(a, lane);
  }
  if (lane < 16) ldsq[lane] = a;
  u64 h = shfl64(a, 15);
  hf = unford((uint)(h >> 32));
  qcount = 16;
  return a;
}

__global__ __launch_bounds__(256) void knn_pool_k(const float4* __restrict__ cFs,
                                                  const ushort* __restrict__ ord,
                                                  const float2* __restrict__ sg,
                                                  const ushort* __restrict__ qsrt,
                                                  const float* __restrict__ coords,
                                                  const int* __restrict__ keep,
                                                  const uint* __restrict__ fB32,
                                                  float* __restrict__ out1){
  __shared__ u64 q8[4][2][128];
  int tid = threadIdx.x, lane = tid & 63;
  int wv = tid >> 6;
  int p0 = blockIdx.x * 8 + wv * 2;     // sorted-position; block = 8 norm-adjacent queries
  int n = p0 >> 11;
  int i0 = (int)qsrt[(n << 11) + (p0 & 2047)];
  int i1 = (int)qsrt[(n << 11) + (p0 & 2047) + 1];
  u64* qlA = q8[wv][0];
  u64* qlB = q8[wv][1];
  float4 qa, qb;
  {
    const float* c0p = coords + ((size_t)keep[i0] * 8 + n) * 3;
    const float* c1p = coords + ((size_t)keep[i1] * 8 + n) * 3;
    qa.x = c0p[0]; qa.y = c0p[1]; qa.z = c0p[2];
    qb.x = c1p[0]; qb.y = c1p[1]; qb.z = c1p[2];
    {
      #pragma clang fp contract(off)
      qa.w = qa.x*qa.x + qa.y*qa.y + qa.z*qa.z;
    }
    {
      #pragma clang fp contract(off)
      qb.w = qb.x*qb.x + qb.y*qb.y + qb.z*qb.z;
    }
  }
  float skA = sqrtf(qa.w), skB = sqrtf(qb.w);
  const float4* base = cFs + ((size_t)n << 13);
  const ushort* ordn = ord + (n << 13);
  const float2* sgn = sg + n * 16;

  float hfA = 3.4e38f, hfrA = 3.4e38f; int qcA = 0;
  float hfB = 3.4e38f, hfrB = 3.4e38f; int qcB = 0;

  #define PROCQ(q, hfr, hf, qc, ql, e, bal, jidx, cf) { \
    if (bal){ \
      if (e <= hfr){ \
        float d2; \
        { \
          _Pragma("clang fp contract(off)") \
          float dot = q.x*(cf).x + q.y*(cf).y + q.z*(cf).z; \
          d2 = (q.w + (cf).w) - 2.0f * dot; \
        } \
        uint ol = (uint)ordn[jidx]; \
        int rel = __builtin_amdgcn_mbcnt_lo((uint)bal, 0); \
        rel = __builtin_amdgcn_mbcnt_hi((uint)(bal >> 32), rel); \
        ql[qc + rel] = ((u64)ford(d2) << 32) | ol; \
      } \
      qc += __popcll(bal); \
      if (qc >= 49){ drain(ql, qc, hf, lane); hfr = hf + 1e-3f; } \
    } \
  }
  #define PROC2(cf, jidx) { \
    float dA = __builtin_fmaf(qa.x,(cf).x, __builtin_fmaf(qa.y,(cf).y, qa.z*(cf).z)); \
    float dB = __builtin_fmaf(qb.x,(cf).x, __builtin_fmaf(qb.y,(cf).y, qb.z*(cf).z)); \
    float eA = __builtin_fmaf(-2.0f, dA, qa.w + (cf).w); \
    float eB = __builtin_fmaf(-2.0f, dB, qb.w + (cf).w); \
    if (__ballot(fminf(eA, eB) <= fmaxf(hfrA, hfrB))){ \
      u64 balA = __ballot(eA <= hfrA); \
      u64 balB = __ballot(eB <= hfrB); \
      PROCQ(qa, hfrA, hfA, qcA, qlA, eA, balA, jidx, cf) \
      PROCQ(qb, hfrB, hfB, qcB, qlB, eB, balB, jidx, cf) \
    } \
  }

  int gstart = 0;
  {
    float skM = 0.5f * (skA + skB);
    #pragma unroll
    for (int g = 1; g < 16; ++g) if (sgn[g].x <= skM) gstart = g;
  }
  for (int step = 0; step < 31; ++step){
    int off = (step + 1) >> 1;
    int g = (step & 1) ? gstart - off : gstart + off;
    if (g < 0 || g > 15) continue;
    float2 sv = sgn[g];
    float la = fmaxf(fmaxf(sv.x - skA, skA - sv.y), 0.f);
    float lb = fmaxf(fmaxf(sv.x - skB, skB - sv.y), 0.f);
    if (la * la > hfA + 0.01f && lb * lb > hfB + 0.01f) continue;  // provably safe skip
    const float4* p = base + (g << 9) + lane;
    float4 c0 = p[0];
    float4 c1 = p[64];
    float4 c2 = p[128];
    float4 c3 = p[192];
    float4 c4 = p[256];
    float4 c5 = p[320];
    float4 c6 = p[384];
    float4 c7 = p[448];
    int j0 = (g << 9) + lane;
    PROC2(c0, j0);
    PROC2(c1, j0 + 64);
    PROC2(c2, j0 + 128);
    PROC2(c3, j0 + 192);
    PROC2(c4, j0 + 256);
    PROC2(c5, j0 + 320);
    PROC2(c6, j0 + 384);
    PROC2(c7, j0 + 448);
  }
  u64 aA = drain(qlA, qcA, hfA, lane);
  u64 aB = drain(qlB, qcB, hfB, lane);
  #undef PROC2
  #undef PROCQ

  const uint* frow = fB32 + ((size_t)(n << 11) << 6);
  float a0 = -3.4e38f, a1v = -3.4e38f, b0 = -3.4e38f, b1v = -3.4e38f;
  #pragma unroll
  for (int k = 0; k < 16; ++k){
    int idxA = (int)(shfl64(aA, k) & 2047u);            // fmod(L2) quirk
    int idxB = (int)(shfl64(aB, k) & 2047u);
    uint uA = frow[((size_t)idxA << 6) + lane];
    uint uB = frow[((size_t)idxB << 6) + lane];
    a0  = fmaxf(a0,  __uint_as_float((uA & 0xFFFFu) << 16));
    a1v = fmaxf(a1v, __uint_as_float((uA >> 16) << 16));
    b0  = fmaxf(b0,  __uint_as_float((uB & 0xFFFFu) << 16));
    b1v = fmaxf(b1v, __uint_as_float((uB >> 16) << 16));
  }
  float2* oA = (float2*)(out1 + (size_t)(i0 * 8 + n) * 128);
  float2* oB = (float2*)(out1 + (size_t)(i1 * 8 + n) * 128);
  oA[lane] = make_float2(a0, a1v);
  oB[lane] = make_float2(b0, b1v);
}

extern "C" void kernel_launch(void* const* d_in, const int* in_sizes, int n_in,
                              void* d_out, int out_size, void* d_ws, size_t ws_size,
                              hipStream_t stream){
  const float* coords = (const float*)d_in[0];
  const float* feat   = (const float*)d_in[1];
  const float* w1     = (const float*)d_in[2];
  const float* g1     = (const float*)d_in[3];
  const float* b1     = (const float*)d_in[4];
  const float* w2     = (const float*)d_in[5];
  const float* g2     = (const float*)d_in[6];
  const float* b2     = (const float*)d_in[7];
  const int*   keep   = (const int*)d_in[8];
  float* out0 = (float*)d_out;                    // keep_coords [2048,8,3]
  float* out1 = out0 + 49152;                     // pool_features [2048,8,128]

  char* ws = (char*)d_ws;
  float4* cFs = (float4*)ws;                      // [N][L] sorted f32x4 : 1 MB
  ushort* fB  = (ushort*)(ws + (1 << 20));        // [N][L2][128] bf16 : 4 MB
  ushort* pw1 = (ushort*)(ws + (5 << 20));        // 16 KB packed w1
  ushort* pw2 = pw1 + 8192;                       // 32 KB packed w2
  ushort* ord = (ushort*)(ws + (5 << 20) + (64 << 10));   // [N][L] u16 : 128 KB
  float2* sg  = (float2*)(ws + (5 << 20) + (256 << 10));  // [N][16] f32x2 : 1 KB
  ushort* qsrt= (ushort*)(ws + (5 << 20) + (257 << 10));  // [N][L2] u16 : 32 KB
  float4* cT  = (float4*)(ws + (6 << 20));        // [N][L] unsorted f32x4 : 1 MB

  hipLaunchKernelGGL(prep_k, dim3(544), dim3(256), 0, stream,
                     coords, keep, w1, w2, cT, out0, pw1, pw2);
  hipLaunchKernelGGL(mid_k, dim3(272), dim3(256), 0, stream,
                     feat, pw1, g1, b1, pw2, g2, b2, (uint*)fB,
                     cT, keep, cFs, ord, sg, qsrt);
  hipLaunchKernelGGL(knn_pool_k, dim3(2048), dim3(256), 0, stream,
                     cFs, ord, sg, qsrt, coords, keep, (const uint*)fB, out1);
}